// Round 5
// baseline (564.800 us; speedup 1.0000x reference)
//
#include <hip/hip_runtime.h>
#include <math.h>

#define B_  8
#define L_  2500
#define D_  512
#define Y_  8921
#define LP  2560    // L padded
#define YP  8960    // Y padded to 140*64

// ws layout: fp16 X[B_][LP][D_]
//          | G fragment-major: [yt(140)][kk2(16)][mi(8)][lane(64)][8]
//            (G row pairs U (sub 0-7) / F (sub 8-15) per 16-row group)
// then fp32  denG[B_][YP] | numG[B_][YP]
#define WS_F16_HALVES  (B_ * LP * D_ + 2 * YP * D_)
#define ACC_FLOATS     (2 * B_ * YP)

typedef _Float16 f16x8 __attribute__((ext_vector_type(8)));
typedef float    f32x4 __attribute__((ext_vector_type(4)));

__device__ __forceinline__ void load_lds16(const _Float16* g, _Float16* l) {
  __builtin_amdgcn_global_load_lds(
      (const __attribute__((address_space(1))) unsigned int*)g,
      (__attribute__((address_space(3))) unsigned int*)l, 16, 0, 0);
}

__global__ void k_convert(const float* __restrict__ x,
                          const float* __restrict__ Uw,
                          const float* __restrict__ Fw,
                          _Float16* __restrict__ ws,
                          float* __restrict__ loss_slot) {
  if (blockIdx.x == 0 && threadIdx.x == 0) *loss_slot = 0.0f;
  const int NX = B_ * LP * (D_ / 8);   // 1310720 slots
  int idx = blockIdx.x * 256 + threadIdx.x;
  if (idx < ACC_FLOATS) ((float*)(ws + WS_F16_HALVES))[idx] = 0.0f;
  const float* src = nullptr;
  if (idx < NX) {
    int b  = idx / (LP * 64);
    int r  = idx - b * (LP * 64);
    int l  = r >> 6;
    int d8 = r & 63;
    if (l < L_) src = x + (((long)b * L_ + l) * D_ + d8 * 8);
  } else {
    // G fragment-major slot: [yt][kk2][mi][lane]
    int u    = idx - NX;
    int lane = u & 63;
    int mi   = (u >> 6) & 7;
    int kk2  = (u >> 9) & 15;
    int yt   = u >> 13;
    int grow = yt * 128 + mi * 16 + (lane & 15);   // global G row
    int sub  = grow & 15;
    int y    = (grow >> 4) * 8 + (sub & 7);
    int k8   = kk2 * 4 + (lane >> 4);              // 8-elem k granule
    if (y < Y_) src = (sub < 8 ? Uw : Fw) + (long)y * D_ + k8 * 8;
  }
  f16x8 o;
  if (src) {
    const float4* s4 = (const float4*)src;
    float4 a = s4[0], c = s4[1];
    o[0] = (_Float16)a.x; o[1] = (_Float16)a.y; o[2] = (_Float16)a.z; o[3] = (_Float16)a.w;
    o[4] = (_Float16)c.x; o[5] = (_Float16)c.y; o[6] = (_Float16)c.z; o[7] = (_Float16)c.w;
  } else {
    for (int i = 0; i < 8; ++i) o[i] = (_Float16)0.0f;
  }
  ((f16x8*)ws)[idx] = o;
}

// Round 5: 8-wave 4-phase lockstep schedule (m196/m201 structure). Identical
// to round 4 EXCEPT the prologue race fix: round 4 issued st(0) but entered
// the loop without vmcnt-retiring it, so the FIRST quadrant's ds_reads
// (issued pre-barrier, pre-wait by design) raced the st(0) DMA -> sporadic
// stale-LDS reads -> absmax 3.7e-2. Fix: prologue s_waitcnt vmcnt(8)
// (retires st(0)+st(1), keeps au(0) in flight) + s_barrier before the loop.
// Steady state was already race-free: buffer s is vmcnt-retired by every
// wave at step s-1's q0 wait, >=4 barriers before any step-s read; stage
// writes target the buffer whose readers all lgkm-retired before the
// previous step-end barrier.
__global__ __launch_bounds__(512, 2)
void k_attn(const _Float16* __restrict__ ws,
            float* __restrict__ accG) {
  __shared__ __align__(16) _Float16 XT[49152];   // 3 x (256 rows x 64 halves)

  const int tid  = threadIdx.x;
  const int lane = tid & 63;
  const int wave = tid >> 6;           // 0..7
  const int wy = wave >> 1;            // 0..3: G quarter (64 G rows = 32 y)
  const int wl = wave & 1;             // 0..1: l-half (128 cols)
  const int yt = blockIdx.x;           // 0..69 (128 labels each)
  const int b  = blockIdx.y;
  const int lh = blockIdx.z;

  const _Float16* Xg = ws + (long)b * LP * D_ + (long)lh * (LP / 2) * D_;
  // fragment-major G base: original-layout group g=wy>>1, half h=wy&1
  const _Float16* Ga = ws + (long)B_ * LP * D_
                          + (long)(yt * 2 + (wy >> 1)) * (128 * 512)
                          + (wy & 1) * (4 * 512) + lane * 8;

  // X staging: 32 segments of 1KB (8 rows x 64 halves); 4 per wave.
  const int srow = lane >> 3;
  const int sg8  = ((lane & 7) ^ srow) * 8;
  const _Float16* xbase = Xg + (long)(wave * 32 + srow) * D_ + sg8;
  const int ldst = wave * 2048;        // halves offset of this wave's segs

  // compute geometry
  const int xrow = wl * 128 + (lane & 15);
  const int r7   = lane & 7;
  const int gb   = lane >> 4;
  const bool sLow = (lane < 32);

  float redP[4][4];   // den partials (lanes 0-31) / num partials (lanes 32-63)
  #pragma unroll
  for (int i = 0; i < 4; ++i)
    for (int v = 0; v < 4; ++v) redP[i][v] = 0.0f;

  // rotating buffer offsets (halves): read, mid, write(s+2)
  int ofR = 0, of1 = 16384, ofW = 32768;

  // ---- prologue: issue st(0)->buf0, st(1)->buf1, au(0) (order pinned) ----
  #pragma unroll
  for (int i = 0; i < 4; ++i)
    load_lds16(xbase + i * 4096, XT + 0 + ldst + i * 512);
  __builtin_amdgcn_sched_barrier(0);
  #pragma unroll
  for (int i = 0; i < 4; ++i)
    load_lds16(xbase + 64 + i * 4096, XT + 16384 + ldst + i * 512);
  __builtin_amdgcn_sched_barrier(0);
  f16x8 au[2][4];
  #pragma unroll
  for (int ks = 0; ks < 2; ++ks)
    #pragma unroll
    for (int mi = 0; mi < 4; ++mi)
      au[ks][mi] = *(const f16x8*)(Ga + (size_t)ks * 4096 + mi * 512);
  __builtin_amdgcn_sched_barrier(0);
  // RACE FIX: retire st(0)+st(1) (oldest 8 of 16 outstanding; au(0) stays in
  // flight) and barrier, so the first quadrant's ds_reads see staged data.
  asm volatile("s_waitcnt vmcnt(8)" ::: "memory");
  __builtin_amdgcn_s_barrier();
  __builtin_amdgcn_sched_barrier(0);

  #pragma unroll 1
  for (int lt = 0; lt < 5; ++lt) {
    f32x4 acc[4][8];
    #pragma unroll
    for (int mi = 0; mi < 4; ++mi)
      for (int ni = 0; ni < 8; ++ni) {
        f32x4 z = {0.0f, 0.0f, 0.0f, 0.0f};
        acc[mi][ni] = z;
      }
    #pragma unroll 1
    for (int kk = 0; kk < 8; ++kk) {
      const int s   = lt * 8 + kk;
      const int kkn = (kk + 1) & 7;
      const int sp  = (s + 2 < 40) ? s + 2 : 39;   // stage lookahead 2 (tail: dummy)
      const long ofs_next = (long)(sp >> 3) * (256 * D_) + (long)(sp & 7) * 64;
      #pragma unroll
      for (int q = 0; q < 4; ++q) {
        // this quadrant's B fragments, issued pre-barrier
        f16x8 bq[2][2];
        #pragma unroll
        for (int ks = 0; ks < 2; ++ks)
          #pragma unroll
          for (int j = 0; j < 2; ++j)
            bq[ks][j] = *(const f16x8*)&XT[ofR + (xrow + (2 * q + j) * 16) * 64
                                           + (((ks * 4 + gb) ^ r7) * 8)];
        __builtin_amdgcn_sched_barrier(0);
        // one stage seg per phase -> buf[(s+2)%3]
        load_lds16(xbase + ofs_next + q * 4096, XT + ofW + ldst + q * 512);
        __builtin_amdgcn_sched_barrier(0);
        __builtin_amdgcn_s_barrier();
        if (q == 0)
          asm volatile("s_waitcnt vmcnt(1) lgkmcnt(0)" ::: "memory");
        else
          asm volatile("s_waitcnt lgkmcnt(0)" ::: "memory");
        __builtin_amdgcn_sched_barrier(0);
        __builtin_amdgcn_s_setprio(1);
        #pragma unroll
        for (int ks = 0; ks < 2; ++ks)
          #pragma unroll
          for (int mi = 0; mi < 4; ++mi)
            #pragma unroll
            for (int j = 0; j < 2; ++j)
              acc[mi][2 * q + j] = __builtin_amdgcn_mfma_f32_16x16x32_f16(
                  au[ks][mi], bq[ks][j], acc[mi][2 * q + j], 0, 0, 0);
        __builtin_amdgcn_s_setprio(0);
        __builtin_amdgcn_sched_barrier(0);
        if (q == 3) {
          if (kk == 7) {
            // epilogue: low lanes hold S -> e=exp(S), den += e; shfl_xor(e,32)
            // hands e to the C half; upper lanes num += e * C. Pad cols: e=1
            // exact, C=0.
            #pragma unroll
            for (int mi = 0; mi < 4; ++mi)
              for (int ni = 0; ni < 8; ++ni)
                #pragma unroll
                for (int v = 0; v < 4; ++v) {
                  float a = acc[mi][ni][v];
                  float e = __expf(a);
                  float p = __shfl_xor(e, 32, 64);
                  redP[mi][v] += sLow ? e : p * a;
                }
          }
          // au(s+1): G repeats per lt so kkn addressing is loop-uniform; at
          // kk==7 this IS next lt's au(0) (true dummy only at the very end).
          #pragma unroll
          for (int ks = 0; ks < 2; ++ks)
            #pragma unroll
            for (int mi = 0; mi < 4; ++mi)
              au[ks][mi] = *(const f16x8*)(Ga + (size_t)(kkn * 2 + ks) * 4096 + mi * 512);
          __builtin_amdgcn_sched_barrier(0);
          __builtin_amdgcn_s_barrier();   // step-end: buf reads done before next overwrite
          int t = ofR; ofR = of1; of1 = ofW; ofW = t;
        }
      }
    }
  }

  // reduce over the 16 columns sharing each label row
  for (int m = 1; m < 16; m <<= 1)
    #pragma unroll
    for (int mi = 0; mi < 4; ++mi)
      for (int v = 0; v < 4; ++v)
        redP[mi][v] += __shfl_xor(redP[mi][v], m, 64);
  if ((lane & 15) == 0) {
    float* dst = accG + (sLow ? 0 : B_ * YP);   // den | num
    #pragma unroll
    for (int mi = 0; mi < 4; ++mi)
      for (int v = 0; v < 4; ++v) {
        int y = yt * 128 + wy * 32 + mi * 8 + ((lane >> 4) & 1) * 4 + v;
        atomicAdd(&dst[b * YP + y], redP[mi][v]);
      }
  }
}

__global__ void k_final(const float* __restrict__ accG,
                        const float* __restrict__ fb,
                        float* __restrict__ out) {
  int id = blockIdx.x * 256 + threadIdx.x;
  if (id >= B_ * Y_) return;
  int b = id / Y_, y = id - b * Y_;
  float den = accG[b * YP + y] - (float)(LP - L_);
  out[id] = accG[B_ * YP + b * YP + y] / den + fb[y];
}

__global__ void k_loss(const float* __restrict__ y,
                       const float* __restrict__ t,
                       float* __restrict__ loss) {
  float p = 0.0f;
  for (int i = blockIdx.x * 256 + threadIdx.x; i < B_ * Y_; i += gridDim.x * 256) {
    float v = y[i], tg = t[i];
    p += fmaxf(v, 0.0f) - v * tg + log1pf(__expf(-fabsf(v)));
  }
  for (int m = 32; m; m >>= 1) p += __shfl_down(p, m, 64);
  __shared__ float wsum[4];
  int lane = threadIdx.x & 63, wv = threadIdx.x >> 6;
  if (lane == 0) wsum[wv] = p;
  __syncthreads();
  if (threadIdx.x == 0) {
    float s = wsum[0] + wsum[1] + wsum[2] + wsum[3];
    atomicAdd(loss, s * (1.0f / (float)(B_ * Y_)));
  }
}

extern "C" void kernel_launch(void* const* d_in, const int* in_sizes, int n_in,
                              void* d_out, int out_size, void* d_ws, size_t ws_size,
                              hipStream_t stream) {
  (void)in_sizes; (void)n_in; (void)out_size; (void)ws_size;
  const float* x       = (const float*)d_in[0];
  const float* target  = (const float*)d_in[1];
  const float* U_w     = (const float*)d_in[3];
  const float* final_w = (const float*)d_in[4];
  const float* final_b = (const float*)d_in[5];
  float* out = (float*)d_out;
  _Float16* ws = (_Float16*)d_ws;
  float* accG = (float*)(ws + WS_F16_HALVES);

  k_convert<<<9600, 256, 0, stream>>>(x, U_w, final_w, ws, out + B_ * Y_);

  dim3 g(YP / 128, B_, 2);
  k_attn<<<g, 512, 0, stream>>>(ws, accG);

  k_final<<<(B_ * Y_ + 255) / 256, 256, 0, stream>>>(accG, final_b, out);
  k_loss<<<140, 256, 0, stream>>>(out, target, out + B_ * Y_);
}

// Round 6
// 548.843 us; speedup vs baseline: 1.0291x; 1.0291x over previous
//
#include <hip/hip_runtime.h>
#include <math.h>

#define B_  8
#define L_  2500
#define D_  512
#define Y_  8921
#define LP  2560    // L padded
#define YP  8960    // Y padded to 140*64

// ws layout: fp16 X[B_][LP][D_]
//          | G fragment-major: [yt(140)][kk2(16)][mi(8)][lane(64)][8]
//            (G row pairs U (sub 0-7) / F (sub 8-15) per 16-row group)
// then fp32  denG[B_][YP] | numG[B_][YP]
#define WS_F16_HALVES  (B_ * LP * D_ + 2 * YP * D_)
#define ACC_FLOATS     (2 * B_ * YP)

typedef _Float16 f16x8 __attribute__((ext_vector_type(8)));
typedef float    f32x4 __attribute__((ext_vector_type(4)));

__device__ __forceinline__ void load_lds16(const _Float16* g, _Float16* l) {
  __builtin_amdgcn_global_load_lds(
      (const __attribute__((address_space(1))) unsigned int*)g,
      (__attribute__((address_space(3))) unsigned int*)l, 16, 0, 0);
}

__global__ void k_convert(const float* __restrict__ x,
                          const float* __restrict__ Uw,
                          const float* __restrict__ Fw,
                          _Float16* __restrict__ ws,
                          float* __restrict__ loss_slot) {
  if (blockIdx.x == 0 && threadIdx.x == 0) *loss_slot = 0.0f;
  const int NX = B_ * LP * (D_ / 8);   // 1310720 slots
  int idx = blockIdx.x * 256 + threadIdx.x;
  if (idx < ACC_FLOATS) ((float*)(ws + WS_F16_HALVES))[idx] = 0.0f;
  const float* src = nullptr;
  if (idx < NX) {
    int b  = idx / (LP * 64);
    int r  = idx - b * (LP * 64);
    int l  = r >> 6;
    int d8 = r & 63;
    if (l < L_) src = x + (((long)b * L_ + l) * D_ + d8 * 8);
  } else {
    // G fragment-major slot: [yt][kk2][mi][lane]
    int u    = idx - NX;
    int lane = u & 63;
    int mi   = (u >> 6) & 7;
    int kk2  = (u >> 9) & 15;
    int yt   = u >> 13;
    int grow = yt * 128 + mi * 16 + (lane & 15);   // global G row
    int sub  = grow & 15;
    int y    = (grow >> 4) * 8 + (sub & 7);
    int k8   = kk2 * 4 + (lane >> 4);              // 8-elem k granule
    if (y < Y_) src = (sub < 8 ? Uw : Fw) + (long)y * D_ + k8 * 8;
  }
  f16x8 o;
  if (src) {
    const float4* s4 = (const float4*)src;
    float4 a = s4[0], c = s4[1];
    o[0] = (_Float16)a.x; o[1] = (_Float16)a.y; o[2] = (_Float16)a.z; o[3] = (_Float16)a.w;
    o[4] = (_Float16)c.x; o[5] = (_Float16)c.y; o[6] = (_Float16)c.z; o[7] = (_Float16)c.w;
  } else {
    for (int i = 0; i < 8; ++i) o[i] = (_Float16)0.0f;
  }
  ((f16x8*)ws)[idx] = o;
}

// Round 6: round-0 kernel (the best measured: 450 µs, MfmaUtil 38.8) with an
// XCD-LOCALITY SWIZZLE (T1) — the one lever not yet tried. Diagnosis: the
// working set is only 39 MB (X 21 + G 18.4) yet FETCH_SIZE = 710 MB (18x
// over-fetch): the default grid round-robins blocks across 8 XCDs so each
// 4 MB XCD-L2 sees ~30 MB of demand -> thrash -> au/stage loads take L3/HBM
// latency (600-900 cyc) that 2-waves/SIMD lockstep can't hide. Remap:
// dispatch sends block i to XCD i%8, so decode
//   b = bid & 7          -> each XCD owns ONE batch's X half-pair (2.6 MB)
//   lh = (bid>>3) & 1    -> both l-halves co-resident,
//   yt = bid >> 4        -> lh0/lh1 sweep yt IN SYNC -> co-resident blocks
//                           share ~32 consecutive G tiles (~4 MB)
// Per-XCD L2 demand ~30 MB -> ~7 MB. Pure index bijection; no other change.
__global__ __launch_bounds__(256, 2)
void k_attn(const _Float16* __restrict__ ws,
            float* __restrict__ accG) {
  __shared__ __align__(16) _Float16 XT[16384];   // 256 rows x 64 halves

  const int tid  = threadIdx.x;
  const int lane = tid & 63;
  const int wave = tid >> 6;           // 0..3
  const int wy = wave & 1;             // G-half (64 G rows = 32 y)
  const int wl = wave >> 1;            // l-half (128 cols)
  const int bid = blockIdx.x;          // 0..2239
  const int b   = bid & 7;             // XCD id (dispatch: bid % 8)
  const int lh  = (bid >> 3) & 1;
  const int yt  = bid >> 4;            // 0..139 (64 labels each)

  const _Float16* Xg = ws + (long)b * LP * D_ + (long)lh * (LP / 2) * D_;
  // fragment-major G base for this yt block + this wave's row-half + lane
  const _Float16* Ga = ws + (long)B_ * LP * D_ + (long)yt * (128 * 512)
                          + (wy * 4) * 512 + lane * 8;

  // X staging: 32 segments of 1KB (8 rows x 64 halves); 8 per wave
  const int srow = lane >> 3;
  const int sg8  = ((lane & 7) ^ srow) * 8;
  const _Float16* xsrc[8];
  _Float16*       xdst[8];
  #pragma unroll
  for (int i = 0; i < 8; ++i) {
    int seg = wave * 8 + i;
    xsrc[i] = Xg + (long)(seg * 8 + srow) * D_ + sg8;   // + lt*256 rows later
    xdst[i] = XT + seg * 512;
  }

  // compute geometry
  const int xrow = wl * 128 + (lane & 15);
  const int r7   = lane & 7;
  const int gb   = lane >> 4;
  const bool sLow = (lane < 32);

  float redP[4][4];   // den partials (lanes 0-31) / num partials (lanes 32-63)
  #pragma unroll
  for (int i = 0; i < 4; ++i)
    for (int v = 0; v < 4; ++v) redP[i][v] = 0.0f;

  for (int lt = 0; lt < 5; ++lt) {
    f32x4 acc[4][8];
    #pragma unroll
    for (int mi = 0; mi < 4; ++mi)
      for (int ni = 0; ni < 8; ++ni) {
        f32x4 z = {0.0f, 0.0f, 0.0f, 0.0f};
        acc[mi][ni] = z;
      }
    const long xofs = (long)lt * 256 * D_;
    for (int kkstep = 0; kkstep < 8; ++kkstep) {
      // A-fragments direct from global (L2) — issued before the barriers so
      // their latency hides under the X stage + drain window
      f16x8 au[2][4];
      #pragma unroll
      for (int ks = 0; ks < 2; ++ks)
        #pragma unroll
        for (int mi = 0; mi < 4; ++mi)
          au[ks][mi] = *(const f16x8*)(Ga + (size_t)(kkstep * 2 + ks) * 4096 + mi * 512);
      __syncthreads();
      #pragma unroll
      for (int i = 0; i < 8; ++i)
        load_lds16(xsrc[i] + xofs + kkstep * 64, xdst[i]);
      __syncthreads();
      #pragma unroll
      for (int ks = 0; ks < 2; ++ks) {
        int off = (((ks * 4 + gb) ^ r7) * 8);
        f16x8 bx[8];
        #pragma unroll
        for (int ni = 0; ni < 8; ++ni)
          bx[ni] = *(const f16x8*)&XT[(xrow + ni * 16) * 64 + off];
        #pragma unroll
        for (int mi = 0; mi < 4; ++mi)
          #pragma unroll
          for (int ni = 0; ni < 8; ++ni)
            acc[mi][ni] = __builtin_amdgcn_mfma_f32_16x16x32_f16(au[ks][mi], bx[ni], acc[mi][ni], 0, 0, 0);
      }
    }
    // epilogue: low lanes hold S -> e=exp(S), den += e; shfl_xor(e,32) hands e
    // to the C half; upper lanes num += e * C. Pad cols: e=1 exact, C=0.
    #pragma unroll
    for (int mi = 0; mi < 4; ++mi)
      for (int ni = 0; ni < 8; ++ni)
        #pragma unroll
        for (int v = 0; v < 4; ++v) {
          float a = acc[mi][ni][v];
          float e = __expf(a);
          float p = __shfl_xor(e, 32, 64);
          redP[mi][v] += sLow ? e : p * a;
        }
  }

  // reduce over the 16 columns sharing each label row
  for (int m = 1; m < 16; m <<= 1)
    #pragma unroll
    for (int mi = 0; mi < 4; ++mi)
      for (int v = 0; v < 4; ++v)
        redP[mi][v] += __shfl_xor(redP[mi][v], m, 64);
  if ((lane & 15) == 0) {
    float* dst = accG + (sLow ? 0 : B_ * YP);   // den | num
    #pragma unroll
    for (int mi = 0; mi < 4; ++mi)
      for (int v = 0; v < 4; ++v) {
        int y = yt * 64 + wy * 32 + mi * 8 + ((lane >> 4) & 1) * 4 + v;
        atomicAdd(&dst[b * YP + y], redP[mi][v]);
      }
  }
}

__global__ void k_final(const float* __restrict__ accG,
                        const float* __restrict__ fb,
                        float* __restrict__ out) {
  int id = blockIdx.x * 256 + threadIdx.x;
  if (id >= B_ * Y_) return;
  int b = id / Y_, y = id - b * Y_;
  float den = accG[b * YP + y] - (float)(LP - L_);
  out[id] = accG[B_ * YP + b * YP + y] / den + fb[y];
}

__global__ void k_loss(const float* __restrict__ y,
                       const float* __restrict__ t,
                       float* __restrict__ loss) {
  float p = 0.0f;
  for (int i = blockIdx.x * 256 + threadIdx.x; i < B_ * Y_; i += gridDim.x * 256) {
    float v = y[i], tg = t[i];
    p += fmaxf(v, 0.0f) - v * tg + log1pf(__expf(-fabsf(v)));
  }
  for (int m = 32; m; m >>= 1) p += __shfl_down(p, m, 64);
  __shared__ float wsum[4];
  int lane = threadIdx.x & 63, wv = threadIdx.x >> 6;
  if (lane == 0) wsum[wv] = p;
  __syncthreads();
  if (threadIdx.x == 0) {
    float s = wsum[0] + wsum[1] + wsum[2] + wsum[3];
    atomicAdd(loss, s * (1.0f / (float)(B_ * Y_)));
  }
}

extern "C" void kernel_launch(void* const* d_in, const int* in_sizes, int n_in,
                              void* d_out, int out_size, void* d_ws, size_t ws_size,
                              hipStream_t stream) {
  (void)in_sizes; (void)n_in; (void)out_size; (void)ws_size;
  const float* x       = (const float*)d_in[0];
  const float* target  = (const float*)d_in[1];
  const float* U_w     = (const float*)d_in[3];
  const float* final_w = (const float*)d_in[4];
  const float* final_b = (const float*)d_in[5];
  float* out = (float*)d_out;
  _Float16* ws = (_Float16*)d_ws;
  float* accG = (float*)(ws + WS_F16_HALVES);

  k_convert<<<9600, 256, 0, stream>>>(x, U_w, final_w, ws, out + B_ * Y_);

  k_attn<<<2240, 256, 0, stream>>>(ws, accG);

  k_final<<<(B_ * Y_ + 255) / 256, 256, 0, stream>>>(accG, final_b, out);
  k_loss<<<140, 256, 0, stream>>>(out, target, out + B_ * Y_);
}

// Round 7
// 531.963 us; speedup vs baseline: 1.0617x; 1.0317x over previous
//
#include <hip/hip_runtime.h>
#include <math.h>

#define B_  8
#define L_  2500
#define D_  512
#define Y_  8921
#define LP  2560    // L padded
#define YP  8960    // Y padded to 140*64

// ws layout: fp16 X[B_][LP][D_]
//          | G fragment-major: [yt(140)][kk2(16)][mi(8)][lane(64)][8]
//            (G row pairs U (sub 0-7) / F (sub 8-15) per 16-row group)
// then fp32  denG[B_][YP] | numG[B_][YP]
#define WS_F16_HALVES  (B_ * LP * D_ + 2 * YP * D_)
#define ACC_FLOATS     (2 * B_ * YP)

typedef _Float16 f16x8 __attribute__((ext_vector_type(8)));
typedef float    f32x4 __attribute__((ext_vector_type(4)));

__device__ __forceinline__ void load_lds16(const _Float16* g, _Float16* l) {
  __builtin_amdgcn_global_load_lds(
      (const __attribute__((address_space(1))) unsigned int*)g,
      (__attribute__((address_space(3))) unsigned int*)l, 16, 0, 0);
}

__global__ void k_convert(const float* __restrict__ x,
                          const float* __restrict__ Uw,
                          const float* __restrict__ Fw,
                          _Float16* __restrict__ ws,
                          float* __restrict__ loss_slot) {
  if (blockIdx.x == 0 && threadIdx.x == 0) *loss_slot = 0.0f;
  const int NX = B_ * LP * (D_ / 8);   // 1310720 slots
  int idx = blockIdx.x * 256 + threadIdx.x;
  if (idx < ACC_FLOATS) ((float*)(ws + WS_F16_HALVES))[idx] = 0.0f;
  const float* src = nullptr;
  if (idx < NX) {
    int b  = idx / (LP * 64);
    int r  = idx - b * (LP * 64);
    int l  = r >> 6;
    int d8 = r & 63;
    if (l < L_) src = x + (((long)b * L_ + l) * D_ + d8 * 8);
  } else {
    // G fragment-major slot: [yt][kk2][mi][lane]
    int u    = idx - NX;
    int lane = u & 63;
    int mi   = (u >> 6) & 7;
    int kk2  = (u >> 9) & 15;
    int yt   = u >> 13;
    int grow = yt * 128 + mi * 16 + (lane & 15);   // global G row
    int sub  = grow & 15;
    int y    = (grow >> 4) * 8 + (sub & 7);
    int k8   = kk2 * 4 + (lane >> 4);              // 8-elem k granule
    if (y < Y_) src = (sub < 8 ? Uw : Fw) + (long)y * D_ + k8 * 8;
  }
  f16x8 o;
  if (src) {
    const float4* s4 = (const float4*)src;
    float4 a = s4[0], c = s4[1];
    o[0] = (_Float16)a.x; o[1] = (_Float16)a.y; o[2] = (_Float16)a.z; o[3] = (_Float16)a.w;
    o[4] = (_Float16)c.x; o[5] = (_Float16)c.y; o[6] = (_Float16)c.z; o[7] = (_Float16)c.w;
  } else {
    for (int i = 0; i < 8; ++i) o[i] = (_Float16)0.0f;
  }
  ((f16x8*)ws)[idx] = o;
}

// Round 7: INDEPENDENCE AT CONSTANT OCCUPANCY. Registers cap the CU at
// 8 waves (256 unified regs/wave); rounds 0-6 packed them as two 4-wave
// blocks (2 rhythms/CU, 4-wave barriers). Diagnosis by elimination (MFMA
// issue 5% of wall, L2 BW 38%, HBM 11%, LDS ~30%, VALU 30%, three schedule
// variants all ~39% MfmaUtil): latency/convergence-bound. This round keeps
// the per-wave code byte-identical (64G x 128l, acc[4][8], same swizzles)
// but splits blocks to 2 WAVES (128 thr): block = 128G x 128l, one 16 KB X
// stage shared by the pair (wy=0/1, same B from LDS, different A from L2 —
// the old wl-duplicate au fetch disappears, cancelling the extra G sweeps:
// aggregate L2 traffic unchanged). 4 independent blocks/CU -> 4 rhythms,
// 2-wave barrier convergence, 16 KB drains. Grid 4480 = yt(140) x lq(4) x
// b(8), XCD swizzle kept: b = bid & 7.
__global__ __launch_bounds__(128, 2)
void k_attn(const _Float16* __restrict__ ws,
            float* __restrict__ accG) {
  __shared__ __align__(16) _Float16 XT[8192];   // 128 rows x 64 halves

  const int tid  = threadIdx.x;
  const int lane = tid & 63;
  const int wave = tid >> 6;           // 0..1
  const int wy = wave;                 // G-half (64 G rows = 32 y)
  const int bid = blockIdx.x;          // 0..4479
  const int b   = bid & 7;             // XCD id (dispatch: bid % 8)
  const int lq  = (bid >> 3) & 3;      // l quarter (640 cols)
  const int yt  = bid >> 5;            // 0..139 (64 labels each)

  const _Float16* Xg = ws + (long)b * LP * D_ + (long)lq * 640 * D_;
  // fragment-major G base for this yt block + this wave's row-half + lane
  const _Float16* Ga = ws + (long)B_ * LP * D_ + (long)yt * (128 * 512)
                          + (wy * 4) * 512 + lane * 8;

  // X staging: 16 segments of 1KB (8 rows x 64 halves); 8 per wave
  const int srow = lane >> 3;
  const int sg8  = ((lane & 7) ^ srow) * 8;
  const _Float16* xsrc[8];
  _Float16*       xdst[8];
  #pragma unroll
  for (int i = 0; i < 8; ++i) {
    int seg = wave * 8 + i;
    xsrc[i] = Xg + (long)(seg * 8 + srow) * D_ + sg8;   // + lt*128 rows later
    xdst[i] = XT + seg * 512;
  }

  // compute geometry
  const int xrow = lane & 15;
  const int r7   = lane & 7;
  const int gb   = lane >> 4;
  const bool sLow = (lane < 32);

  float redP[4][4];   // den partials (lanes 0-31) / num partials (lanes 32-63)
  #pragma unroll
  for (int i = 0; i < 4; ++i)
    for (int v = 0; v < 4; ++v) redP[i][v] = 0.0f;

  for (int lt = 0; lt < 5; ++lt) {
    f32x4 acc[4][8];
    #pragma unroll
    for (int mi = 0; mi < 4; ++mi)
      for (int ni = 0; ni < 8; ++ni) {
        f32x4 z = {0.0f, 0.0f, 0.0f, 0.0f};
        acc[mi][ni] = z;
      }
    const long xofs = (long)lt * 128 * D_;
    for (int kkstep = 0; kkstep < 8; ++kkstep) {
      // A-fragments direct from global (L2) — issued before the barriers so
      // their latency hides under the X stage + drain window
      f16x8 au[2][4];
      #pragma unroll
      for (int ks = 0; ks < 2; ++ks)
        #pragma unroll
        for (int mi = 0; mi < 4; ++mi)
          au[ks][mi] = *(const f16x8*)(Ga + (size_t)(kkstep * 2 + ks) * 4096 + mi * 512);
      __syncthreads();
      #pragma unroll
      for (int i = 0; i < 8; ++i)
        load_lds16(xsrc[i] + xofs + kkstep * 64, xdst[i]);
      __syncthreads();
      #pragma unroll
      for (int ks = 0; ks < 2; ++ks) {
        int off = (((ks * 4 + gb) ^ r7) * 8);
        f16x8 bx[8];
        #pragma unroll
        for (int ni = 0; ni < 8; ++ni)
          bx[ni] = *(const f16x8*)&XT[(xrow + ni * 16) * 64 + off];
        #pragma unroll
        for (int mi = 0; mi < 4; ++mi)
          #pragma unroll
          for (int ni = 0; ni < 8; ++ni)
            acc[mi][ni] = __builtin_amdgcn_mfma_f32_16x16x32_f16(au[ks][mi], bx[ni], acc[mi][ni], 0, 0, 0);
      }
    }
    // epilogue: low lanes hold S -> e=exp(S), den += e; shfl_xor(e,32) hands e
    // to the C half; upper lanes num += e * C. Pad cols: e=1 exact, C=0.
    #pragma unroll
    for (int mi = 0; mi < 4; ++mi)
      for (int ni = 0; ni < 8; ++ni)
        #pragma unroll
        for (int v = 0; v < 4; ++v) {
          float a = acc[mi][ni][v];
          float e = __expf(a);
          float p = __shfl_xor(e, 32, 64);
          redP[mi][v] += sLow ? e : p * a;
        }
  }

  // reduce over the 16 columns sharing each label row
  for (int m = 1; m < 16; m <<= 1)
    #pragma unroll
    for (int mi = 0; mi < 4; ++mi)
      for (int v = 0; v < 4; ++v)
        redP[mi][v] += __shfl_xor(redP[mi][v], m, 64);
  if ((lane & 15) == 0) {
    float* dst = accG + (sLow ? 0 : B_ * YP);   // den | num
    #pragma unroll
    for (int mi = 0; mi < 4; ++mi)
      for (int v = 0; v < 4; ++v) {
        int y = yt * 64 + wy * 32 + mi * 8 + ((lane >> 4) & 1) * 4 + v;
        atomicAdd(&dst[b * YP + y], redP[mi][v]);
      }
  }
}

__global__ void k_final(const float* __restrict__ accG,
                        const float* __restrict__ fb,
                        float* __restrict__ out) {
  int id = blockIdx.x * 256 + threadIdx.x;
  if (id >= B_ * Y_) return;
  int b = id / Y_, y = id - b * Y_;
  float den = accG[b * YP + y] - (float)(LP - L_);
  out[id] = accG[B_ * YP + b * YP + y] / den + fb[y];
}

__global__ void k_loss(const float* __restrict__ y,
                       const float* __restrict__ t,
                       float* __restrict__ loss) {
  float p = 0.0f;
  for (int i = blockIdx.x * 256 + threadIdx.x; i < B_ * Y_; i += gridDim.x * 256) {
    float v = y[i], tg = t[i];
    p += fmaxf(v, 0.0f) - v * tg + log1pf(__expf(-fabsf(v)));
  }
  for (int m = 32; m; m >>= 1) p += __shfl_down(p, m, 64);
  __shared__ float wsum[4];
  int lane = threadIdx.x & 63, wv = threadIdx.x >> 6;
  if (lane == 0) wsum[wv] = p;
  __syncthreads();
  if (threadIdx.x == 0) {
    float s = wsum[0] + wsum[1] + wsum[2] + wsum[3];
    atomicAdd(loss, s * (1.0f / (float)(B_ * Y_)));
  }
}

extern "C" void kernel_launch(void* const* d_in, const int* in_sizes, int n_in,
                              void* d_out, int out_size, void* d_ws, size_t ws_size,
                              hipStream_t stream) {
  (void)in_sizes; (void)n_in; (void)out_size; (void)ws_size;
  const float* x       = (const float*)d_in[0];
  const float* target  = (const float*)d_in[1];
  const float* U_w     = (const float*)d_in[3];
  const float* final_w = (const float*)d_in[4];
  const float* final_b = (const float*)d_in[5];
  float* out = (float*)d_out;
  _Float16* ws = (_Float16*)d_ws;
  float* accG = (float*)(ws + WS_F16_HALVES);

  k_convert<<<9600, 256, 0, stream>>>(x, U_w, final_w, ws, out + B_ * Y_);

  k_attn<<<4480, 128, 0, stream>>>(ws, accG);

  k_final<<<(B_ * Y_ + 255) / 256, 256, 0, stream>>>(accG, final_b, out);
  k_loss<<<140, 256, 0, stream>>>(out, target, out + B_ * Y_);
}